// Round 10
// baseline (403.584 us; speedup 1.0000x reference)
//
#include <hip/hip_runtime.h>
#include <math.h>

// GAT layer, round 10: R9 structure pushed to 8 blocks/CU / 32 waves per CU
// (hardware max) to maximally overlap per-window vmcnt drains across blocks.
// WJ=128, glds width-4 staging (padded LDS stride 132 keeps b128 reads
// conflict-free; width-4 DMA tolerates the pad, unlike width-16).
// N=8192, IN=512, D=64, ALPHA=0.2
//
// ws layout (float-slot units):
//   s1    : [8192] f32                        8192
//   s2    : [8192] f32                        8192
//   hFrag : [256 jblk][4 dt][64 lane] bf16x8 -> 262144 float slots
//   numP  : [2048 blk][4 wv][16 r][64 d] f32  8388608
//   denP  : [2048 blk][4 wv][16 r] f32          131072

#define NN 8192
#define KIN 512
#define DD 64
#define ALPHA 0.2f

#define WJ 128           // j-window per stage (ints)
#define JSPAN 2048       // j-range per block
#define NWIN (JSPAN/WJ)  // 16 windows
#define ASTR 132         // LDS row stride in ints (pad 4: conflict-free b128 reads)
#define ABUF (16 * ASTR) // ints per buffer (8.4 KB)

using floatx4 = __attribute__((ext_vector_type(4))) float;
using bf16x8  = __attribute__((ext_vector_type(8))) __bf16;

__device__ __forceinline__ void glds4(const int* g, int* l) {
    __builtin_amdgcn_global_load_lds((const __attribute__((address_space(1))) void*)g,
                                     (__attribute__((address_space(3))) void*)l, 4, 0, 0);
}

// ------- Kernel 1: fused  h-tile GEMM -> {s1, s2, hFrag}  (h stays on-chip) -------
__global__ __launch_bounds__(256) void k_fused(const float* __restrict__ X,
                                               const float* __restrict__ W,
                                               const float* __restrict__ a,
                                               float* __restrict__ s1,
                                               float* __restrict__ s2,
                                               __bf16* __restrict__ hFrag) {
    __shared__ __align__(16) float smem[3200];  // XT[32*36]+WL[32*64] / reused as hT[32*66]
    float* XT = smem;             // [k][row], stride 36
    float* WL = smem + 32 * 36;   // [k][d]
    float* hT = smem;             // [row][d], stride 66 (reused after final sync)
    const int t = threadIdx.x;
    const int i0 = blockIdx.x * 32;
    const int rb = t >> 5;   // rows rb*4..+3
    const int db = t & 31;   // dims db*2..+1
    float acc[4][2] = {};

    for (int k0 = 0; k0 < KIN; k0 += 32) {
        {
            const int row = t >> 3, kq = t & 7;
            const float4 x4 = *(const float4*)(X + (size_t)(i0 + row) * KIN + k0 + kq * 4);
            XT[(kq * 4 + 0) * 36 + row] = x4.x;
            XT[(kq * 4 + 1) * 36 + row] = x4.y;
            XT[(kq * 4 + 2) * 36 + row] = x4.z;
            XT[(kq * 4 + 3) * 36 + row] = x4.w;
#pragma unroll
            for (int p = 0; p < 2; ++p) {
                const int q = p * 256 + t;  // 0..511
                const int kk = q >> 4, dq = q & 15;
                *(float4*)(WL + kk * 64 + dq * 4) =
                    *(const float4*)(W + (size_t)(k0 + kk) * DD + dq * 4);
            }
        }
        __syncthreads();
#pragma unroll
        for (int k = 0; k < 32; ++k) {
            const float4 xa = *(const float4*)(XT + k * 36 + rb * 4);
            const float2 wb = *(const float2*)(WL + k * 64 + db * 2);
            const float xv[4] = {xa.x, xa.y, xa.z, xa.w};
#pragma unroll
            for (int i = 0; i < 4; ++i) {
                acc[i][0] += xv[i] * wb.x;
                acc[i][1] += xv[i] * wb.y;
            }
        }
        __syncthreads();
    }
#pragma unroll
    for (int i = 0; i < 4; ++i) {
        hT[(rb * 4 + i) * 66 + db * 2 + 0] = acc[i][0];
        hT[(rb * 4 + i) * 66 + db * 2 + 1] = acc[i][1];
    }
    __syncthreads();
    {
        const int r = t >> 3, sub = t & 7;
        float p1 = 0.f, p2 = 0.f;
#pragma unroll
        for (int u = 0; u < 8; ++u) {
            const int d = sub * 8 + u;
            const float v = hT[r * 66 + d];
            p1 += v * a[d];
            p2 += v * a[64 + d];
        }
#pragma unroll
        for (int off = 1; off < 8; off <<= 1) {
            p1 += __shfl_xor(p1, off, 64);
            p2 += __shfl_xor(p2, off, 64);
        }
        if (sub == 0) {
            s1[i0 + r] = p1;
            s2[i0 + r] = p2;
        }
    }
    {
        const int lane = t & 63, dt = t >> 6;
        const int n = lane & 15, q = lane >> 4;
        bf16x8 v;
#pragma unroll
        for (int jj = 0; jj < 8; ++jj)
            v[jj] = (__bf16)hT[(q * 8 + jj) * 66 + dt * 16 + n];
        *(bf16x8*)(hFrag + ((size_t)blockIdx.x * 256 + t) * 8) = v;
    }
}

// ------- Kernel 2: Adj-stream (glds dbuf, 8 blocks/CU) + masked softmax MFMA -------
// 2048 blocks x 256 threads (4 waves); block = 16 rows x 2048 j (j-quarter).
// Wave wv stages rows wv*4..+3 of each 128-j window (8 x 256B glds4) and
// computes K-step wv (per-wave j-partials, reduced in k_final).
__global__ __launch_bounds__(256) void k_attn9(const bf16x8* __restrict__ hFrag,
                                               const int* __restrict__ Adj,
                                               const float* __restrict__ s1,
                                               const float* __restrict__ s2,
                                               float* __restrict__ numP,
                                               float* __restrict__ denP) {
    __shared__ int lds_adj[2 * ABUF];  // 2 x 8.4 KB -> 8 blocks/CU (135 KB)
    const int t = threadIdx.x;
    const int wv = t >> 6, lane = t & 63;
    const int n = lane & 15, q = lane >> 4;
    const int i0 = (blockIdx.x >> 2) * 16;
    const int jb0 = (blockIdx.x & 3) * JSPAN;
    const float s1v = s1[i0 + n];

    bf16x8 ones;
#pragma unroll
    for (int u = 0; u < 8; ++u) ones[u] = (__bf16)1.0f;

    floatx4 acc[5] = {};  // 4 d-tiles + denominator (B = ones); per-wave j-partials

    // ---- stage issuer: window w -> buffer buf (8 x 256B glds4 per wave) ----
    auto issue = [&](int w, int buf) {
        const int jg0 = jb0 + w * WJ;
#pragma unroll
        for (int r4 = 0; r4 < 4; ++r4) {
            const int r = wv * 4 + r4;
            const int* gsrc = Adj + (size_t)(i0 + r) * NN + jg0 + lane;
            int* ldst = lds_adj + buf * ABUF + r * ASTR;  // wave-uniform base
            glds4(gsrc, ldst);
            glds4(gsrc + 64, ldst + 64);
        }
    };

    issue(0, 0);
    issue(1, 1);

#pragma unroll 1
    for (int w = 0; w < NWIN; ++w) {
        const int buf = w & 1;
        __syncthreads();  // drain: this window's (and prefetched) loads landed
        // ---- compute: wave wv handles K-step wv of this window ----
        const int* ldsb = lds_adj + buf * ABUF + n * ASTR;
        {
            const int jg = jb0 + w * WJ + wv * 32 + q * 8;
            const float4 z0 = *(const float4*)(s2 + jg);
            const float4 z1 = *(const float4*)(s2 + jg + 4);
            const int4 m0 = *(const int4*)(ldsb + wv * 32 + q * 8);
            const int4 m1 = *(const int4*)(ldsb + wv * 32 + q * 8 + 4);
            const int am[8] = {m0.x, m0.y, m0.z, m0.w, m1.x, m1.y, m1.z, m1.w};
            const float zz[8] = {z0.x, z0.y, z0.z, z0.w, z1.x, z1.y, z1.z, z1.w};
            bf16x8 af;
#pragma unroll
            for (int u = 0; u < 8; ++u) {
                const float s = s1v + zz[u];
                const float l = fmaxf(s, ALPHA * s);  // leaky-relu (alpha<1)
                const float e = am[u] ? __expf(l) : 0.f;
                af[u] = (__bf16)e;
            }
            const bf16x8* hf = hFrag + (size_t)(jg >> 5) * 4 * 64 + lane;
#pragma unroll
            for (int dt = 0; dt < 4; ++dt)
                acc[dt] = __builtin_amdgcn_mfma_f32_16x16x32_bf16(af, hf[dt * 64], acc[dt], 0, 0, 0);
            acc[4] = __builtin_amdgcn_mfma_f32_16x16x32_bf16(af, ones, acc[4], 0, 0, 0);
        }
        __syncthreads();  // all waves done reading buf before it is overwritten
        if (w + 2 < NWIN) issue(w + 2, buf);
    }

    // ---- per-wave partial writes: D row m = q*4+reg, col d = dt*16+n ----
    const size_t base = ((size_t)blockIdx.x * 4 + wv) * 1024;
#pragma unroll
    for (int dt = 0; dt < 4; ++dt)
#pragma unroll
        for (int r = 0; r < 4; ++r)
            numP[base + (size_t)(q * 4 + r) * 64 + dt * 16 + n] = acc[dt][r];

    if (n == 0) {
#pragma unroll
        for (int r = 0; r < 4; ++r)
            denP[((size_t)blockIdx.x * 4 + wv) * 16 + q * 4 + r] = acc[4][r];
    }
}

// ------- Kernel 3: reduce 16 partials (4 j-quarters x 4 waves) + normalize -------
__global__ __launch_bounds__(256) void k_final(const float* __restrict__ numP,
                                               const float* __restrict__ denP,
                                               float* __restrict__ out) {
    const int idx = blockIdx.x * 256 + threadIdx.x;  // 0..524287
    const int i = idx >> 6, d = idx & 63;
    const int itile = i >> 4, r = i & 15;
    float num = 0.f, den = 0.f;
#pragma unroll
    for (int jq = 0; jq < 4; ++jq) {
        const int b = itile * 4 + jq;
#pragma unroll
        for (int wv = 0; wv < 4; ++wv) {
            num += numP[((size_t)b * 4 + wv) * 1024 + (size_t)r * 64 + d];
            den += denP[((size_t)b * 4 + wv) * 16 + r];
        }
    }
    out[idx] = num / den;
}

extern "C" void kernel_launch(void* const* d_in, const int* in_sizes, int n_in,
                              void* d_out, int out_size, void* d_ws, size_t ws_size,
                              hipStream_t stream) {
    const float* X = (const float*)d_in[0];
    const int* Adj = (const int*)d_in[1];
    const float* W = (const float*)d_in[2];
    const float* a = (const float*)d_in[3];
    float* out = (float*)d_out;

    float* ws = (float*)d_ws;
    float* s1 = ws;                                  // 8192
    float* s2 = s1 + 8192;                           // 8192
    __bf16* hFrag = (__bf16*)(s2 + 8192);            // 262144 float slots
    float* numP = (float*)(s2 + 8192 + 262144);      // 2048*4*1024
    float* denP = numP + 2048 * 4 * 1024;            // 2048*4*16

    k_fused<<<256, 256, 0, stream>>>(X, W, a, s1, s2, hFrag);
    k_attn9<<<2048, 256, 0, stream>>>((const bf16x8*)hFrag, Adj, s1, s2, numP, denP);
    k_final<<<2048, 256, 0, stream>>>(numP, denP, out);
}

// Round 11
// 395.311 us; speedup vs baseline: 1.0209x; 1.0209x over previous
//
#include <hip/hip_runtime.h>
#include <math.h>

// GAT layer, round 11: REVERT to round-9 configuration (best measured:
// 396.8 us). 4 blocks/CU, WJ=256, width-16 global_load_lds double-buffer.
// R10 (8 blocks/CU, WJ=128, width-4) regressed to 403.6 — duty-cycle lever
// saturated at 4 blocks/CU. Cold Adj ingest is pinned at ~2.3 TB/s across 8
// structurally different kernels (R1-R10); attn ~117 us is at that floor.
// N=8192, IN=512, D=64, ALPHA=0.2
//
// ws layout (float-slot units):
//   s1    : [8192] f32                        8192
//   s2    : [8192] f32                        8192
//   hFrag : [256 jblk][4 dt][64 lane] bf16x8 -> 262144 float slots
//   numP  : [1024 blk][4 wv][16 r][64 d] f32  4194304
//   denP  : [1024 blk][4 wv][16 r] f32          65536

#define NN 8192
#define KIN 512
#define DD 64
#define ALPHA 0.2f

#define WJ 256           // j-window per stage (ints)
#define JSPAN 4096       // j-range per block
#define NWIN (JSPAN/WJ)  // 16 windows
#define ASTR 260         // LDS row stride in ints (16B-aligned rows)
#define ABUF (16 * ASTR) // ints per buffer (16.6 KB)

using floatx4 = __attribute__((ext_vector_type(4))) float;
using bf16x8  = __attribute__((ext_vector_type(8))) __bf16;

__device__ __forceinline__ void glds16(const int* g, int* l) {
    __builtin_amdgcn_global_load_lds((const __attribute__((address_space(1))) void*)g,
                                     (__attribute__((address_space(3))) void*)l, 16, 0, 0);
}

// ------- Kernel 1: fused  h-tile GEMM -> {s1, s2, hFrag}  (h stays on-chip) -------
__global__ __launch_bounds__(256) void k_fused(const float* __restrict__ X,
                                               const float* __restrict__ W,
                                               const float* __restrict__ a,
                                               float* __restrict__ s1,
                                               float* __restrict__ s2,
                                               __bf16* __restrict__ hFrag) {
    __shared__ __align__(16) float smem[3200];  // XT[32*36]+WL[32*64] / reused as hT[32*66]
    float* XT = smem;             // [k][row], stride 36
    float* WL = smem + 32 * 36;   // [k][d]
    float* hT = smem;             // [row][d], stride 66 (reused after final sync)
    const int t = threadIdx.x;
    const int i0 = blockIdx.x * 32;
    const int rb = t >> 5;   // rows rb*4..+3
    const int db = t & 31;   // dims db*2..+1
    float acc[4][2] = {};

    for (int k0 = 0; k0 < KIN; k0 += 32) {
        {
            const int row = t >> 3, kq = t & 7;
            const float4 x4 = *(const float4*)(X + (size_t)(i0 + row) * KIN + k0 + kq * 4);
            XT[(kq * 4 + 0) * 36 + row] = x4.x;
            XT[(kq * 4 + 1) * 36 + row] = x4.y;
            XT[(kq * 4 + 2) * 36 + row] = x4.z;
            XT[(kq * 4 + 3) * 36 + row] = x4.w;
#pragma unroll
            for (int p = 0; p < 2; ++p) {
                const int q = p * 256 + t;  // 0..511
                const int kk = q >> 4, dq = q & 15;
                *(float4*)(WL + kk * 64 + dq * 4) =
                    *(const float4*)(W + (size_t)(k0 + kk) * DD + dq * 4);
            }
        }
        __syncthreads();
#pragma unroll
        for (int k = 0; k < 32; ++k) {
            const float4 xa = *(const float4*)(XT + k * 36 + rb * 4);
            const float2 wb = *(const float2*)(WL + k * 64 + db * 2);
            const float xv[4] = {xa.x, xa.y, xa.z, xa.w};
#pragma unroll
            for (int i = 0; i < 4; ++i) {
                acc[i][0] += xv[i] * wb.x;
                acc[i][1] += xv[i] * wb.y;
            }
        }
        __syncthreads();
    }
#pragma unroll
    for (int i = 0; i < 4; ++i) {
        hT[(rb * 4 + i) * 66 + db * 2 + 0] = acc[i][0];
        hT[(rb * 4 + i) * 66 + db * 2 + 1] = acc[i][1];
    }
    __syncthreads();
    {
        const int r = t >> 3, sub = t & 7;
        float p1 = 0.f, p2 = 0.f;
#pragma unroll
        for (int u = 0; u < 8; ++u) {
            const int d = sub * 8 + u;
            const float v = hT[r * 66 + d];
            p1 += v * a[d];
            p2 += v * a[64 + d];
        }
#pragma unroll
        for (int off = 1; off < 8; off <<= 1) {
            p1 += __shfl_xor(p1, off, 64);
            p2 += __shfl_xor(p2, off, 64);
        }
        if (sub == 0) {
            s1[i0 + r] = p1;
            s2[i0 + r] = p2;
        }
    }
    {
        const int lane = t & 63, dt = t >> 6;
        const int n = lane & 15, q = lane >> 4;
        bf16x8 v;
#pragma unroll
        for (int jj = 0; jj < 8; ++jj)
            v[jj] = (__bf16)hT[(q * 8 + jj) * 66 + dt * 16 + n];
        *(bf16x8*)(hFrag + ((size_t)blockIdx.x * 256 + t) * 8) = v;
    }
}

// ------- Kernel 2: Adj-stream (glds dbuf, 4 blocks/CU) + masked softmax MFMA -------
// 1024 blocks x 256 threads (4 waves); block = 16 rows x 4096 j (j-half).
// Wave wv stages rows wv*4..+3 of each 256-j window (4 x 1KB glds) and computes
// K-steps wv*2..+1 (per-wave j-partials, reduced in k_final).
__global__ __launch_bounds__(256) void k_attn8(const bf16x8* __restrict__ hFrag,
                                               const int* __restrict__ Adj,
                                               const float* __restrict__ s1,
                                               const float* __restrict__ s2,
                                               float* __restrict__ numP,
                                               float* __restrict__ denP) {
    __shared__ int lds_adj[2 * ABUF];  // 2 x 16.6 KB -> 4 blocks/CU
    const int t = threadIdx.x;
    const int wv = t >> 6, lane = t & 63;
    const int n = lane & 15, q = lane >> 4;
    const int i0 = (blockIdx.x >> 1) * 16;
    const int jb0 = (blockIdx.x & 1) * JSPAN;
    const float s1v = s1[i0 + n];

    bf16x8 ones;
#pragma unroll
    for (int u = 0; u < 8; ++u) ones[u] = (__bf16)1.0f;

    floatx4 acc[5] = {};  // 4 d-tiles + denominator (B = ones); per-wave j-partials

    // ---- stage issuer: window w -> buffer buf (4 x 1KB glds per wave) ----
    auto issue = [&](int w, int buf) {
        const int jg0 = jb0 + w * WJ;
#pragma unroll
        for (int r4 = 0; r4 < 4; ++r4) {
            const int r = wv * 4 + r4;
            const int* gsrc = Adj + (size_t)(i0 + r) * NN + jg0 + lane * 4;
            int* ldst = lds_adj + buf * ABUF + r * ASTR;  // wave-uniform base
            glds16(gsrc, ldst);
        }
    };

    issue(0, 0);
    issue(1, 1);

#pragma unroll 1
    for (int w = 0; w < NWIN; ++w) {
        const int buf = w & 1;
        __syncthreads();  // drain: this window's (and prefetched) loads landed
        // ---- compute: wave wv handles K-steps wv*2..+1 of this window ----
        const int* ldsb = lds_adj + buf * ABUF + n * ASTR;
#pragma unroll
        for (int k2 = 0; k2 < 2; ++k2) {
            const int ks = wv * 2 + k2;           // 0..7 within window
            const int jg = jb0 + w * WJ + ks * 32 + q * 8;
            const float4 z0 = *(const float4*)(s2 + jg);
            const float4 z1 = *(const float4*)(s2 + jg + 4);
            const int4 m0 = *(const int4*)(ldsb + ks * 32 + q * 8);
            const int4 m1 = *(const int4*)(ldsb + ks * 32 + q * 8 + 4);
            const int am[8] = {m0.x, m0.y, m0.z, m0.w, m1.x, m1.y, m1.z, m1.w};
            const float zz[8] = {z0.x, z0.y, z0.z, z0.w, z1.x, z1.y, z1.z, z1.w};
            bf16x8 af;
#pragma unroll
            for (int u = 0; u < 8; ++u) {
                const float s = s1v + zz[u];
                const float l = fmaxf(s, ALPHA * s);  // leaky-relu (alpha<1)
                const float e = am[u] ? __expf(l) : 0.f;
                af[u] = (__bf16)e;
            }
            const bf16x8* hf = hFrag + (size_t)(jg >> 5) * 4 * 64 + lane;
#pragma unroll
            for (int dt = 0; dt < 4; ++dt)
                acc[dt] = __builtin_amdgcn_mfma_f32_16x16x32_bf16(af, hf[dt * 64], acc[dt], 0, 0, 0);
            acc[4] = __builtin_amdgcn_mfma_f32_16x16x32_bf16(af, ones, acc[4], 0, 0, 0);
        }
        __syncthreads();  // all waves done reading buf before it is overwritten
        if (w + 2 < NWIN) issue(w + 2, buf);
    }

    // ---- per-wave partial writes: D row m = q*4+reg, col d = dt*16+n ----
    const size_t base = ((size_t)blockIdx.x * 4 + wv) * 1024;
#pragma unroll
    for (int dt = 0; dt < 4; ++dt)
#pragma unroll
        for (int r = 0; r < 4; ++r)
            numP[base + (size_t)(q * 4 + r) * 64 + dt * 16 + n] = acc[dt][r];

    if (n == 0) {
#pragma unroll
        for (int r = 0; r < 4; ++r)
            denP[((size_t)blockIdx.x * 4 + wv) * 16 + q * 4 + r] = acc[4][r];
    }
}

// ------- Kernel 3: reduce 8 partials (2 j-halves x 4 waves) + normalize -------
__global__ __launch_bounds__(256) void k_final(const float* __restrict__ numP,
                                               const float* __restrict__ denP,
                                               float* __restrict__ out) {
    const int idx = blockIdx.x * 256 + threadIdx.x;  // 0..524287
    const int i = idx >> 6, d = idx & 63;
    const int itile = i >> 4, r = i & 15;
    float num = 0.f, den = 0.f;
#pragma unroll
    for (int jh = 0; jh < 2; ++jh) {
        const int b = itile * 2 + jh;
#pragma unroll
        for (int wv = 0; wv < 4; ++wv) {
            num += numP[((size_t)b * 4 + wv) * 1024 + (size_t)r * 64 + d];
            den += denP[((size_t)b * 4 + wv) * 16 + r];
        }
    }
    out[idx] = num / den;
}

extern "C" void kernel_launch(void* const* d_in, const int* in_sizes, int n_in,
                              void* d_out, int out_size, void* d_ws, size_t ws_size,
                              hipStream_t stream) {
    const float* X = (const float*)d_in[0];
    const int* Adj = (const int*)d_in[1];
    const float* W = (const float*)d_in[2];
    const float* a = (const float*)d_in[3];
    float* out = (float*)d_out;

    float* ws = (float*)d_ws;
    float* s1 = ws;                                  // 8192
    float* s2 = s1 + 8192;                           // 8192
    __bf16* hFrag = (__bf16*)(s2 + 8192);            // 262144 float slots
    float* numP = (float*)(s2 + 8192 + 262144);      // 1024*4*1024
    float* denP = numP + 1024 * 4 * 1024;            // 1024*4*16

    k_fused<<<256, 256, 0, stream>>>(X, W, a, s1, s2, hFrag);
    k_attn8<<<1024, 256, 0, stream>>>((const bf16x8*)hFrag, Adj, s1, s2, numP, denP);
    k_final<<<2048, 256, 0, stream>>>(numP, denP, out);
}